// Round 1
// baseline (21505.106 us; speedup 1.0000x reference)
//
#include <hip/hip_runtime.h>
#include <hip/hip_bf16.h>

typedef __attribute__((ext_vector_type(4))) float f32x4;
typedef __attribute__((ext_vector_type(8))) short bf16x8;
typedef unsigned short u16;

#define DEV static __device__ __forceinline__

DEV u16 f2bf(float f){
  unsigned v = __float_as_uint(f);
  v += 0x7fffu + ((v >> 16) & 1u);
  return (u16)(v >> 16);
}
DEV float bf2f(u16 u){ return __uint_as_float(((unsigned)u) << 16); }
DEV float sigm(float x){ return 1.0f / (1.0f + __expf(-x)); }
DEV float tanh_(float x){ return 1.0f - 2.0f / (__expf(2.0f * x) + 1.0f); }
DEV bf16x8 ld8(const u16* p){ return *(const bf16x8*)p; }

struct GemmDesc {
  const u16* A; const u16* A2; const u16* W;
  const float* bias; void* out;
  int lda, lda2, ldw, ldo, N, K, K2, flags; // flags: 1=relu, 2=bf16 out
};
struct GemmMulti { GemmDesc d[4]; int nblk[4]; int ndesc; };

template<int NT>
DEV void mm_acc(const u16* ap, const u16* wp, int ldw, int K, f32x4* acc){
  for (int k = 0; k < K; k += 32){
    bf16x8 a = ld8(ap + k);
    #pragma unroll
    for (int nt = 0; nt < NT; ++nt){
      bf16x8 b = ld8(wp + (size_t)(nt * 16) * ldw + k);
      acc[nt] = __builtin_amdgcn_mfma_f32_16x16x32_bf16(a, b, acc[nt], 0, 0, 0);
    }
  }
}

DEV void run_gemm(const GemmDesc& d, int blk){
  const int ntn = d.N >> 6;
  const int bm = blk / ntn, bn = blk - bm * ntn;
  const int w = threadIdx.x >> 6, lane = threadIdx.x & 63;
  const int r = lane & 15, g = lane >> 4;
  const int m0 = bm * 64 + w * 16, n0 = bn * 64;
  f32x4 acc[4];
  #pragma unroll
  for (int i = 0; i < 4; ++i) acc[i] = (f32x4){0.f, 0.f, 0.f, 0.f};
  mm_acc<4>(d.A + (size_t)(m0 + r) * d.lda + g * 8,
            d.W + (size_t)(n0 + r) * d.ldw + g * 8, d.ldw, d.K, acc);
  if (d.A2)
    mm_acc<4>(d.A2 + (size_t)(m0 + r) * d.lda2 + g * 8,
              d.W + (size_t)(n0 + r) * d.ldw + d.K + g * 8, d.ldw, d.K2, acc);
  #pragma unroll
  for (int nt = 0; nt < 4; ++nt){
    #pragma unroll
    for (int i = 0; i < 4; ++i){
      const int row = m0 + g * 4 + i, col = n0 + nt * 16 + r;
      float v = acc[nt][i];
      if (d.bias) v += d.bias[col];
      if (d.flags & 1) v = fmaxf(v, 0.f);
      if (d.flags & 2) ((u16*)d.out)[(size_t)row * d.ldo + col] = f2bf(v);
      else             ((float*)d.out)[(size_t)row * d.ldo + col] = v;
    }
  }
}

__global__ __launch_bounds__(256) void k_gemm_multi(GemmMulti gm){
  int blk = blockIdx.x, di = 0;
  while (di < gm.ndesc - 1 && blk >= gm.nblk[di]){ blk -= gm.nblk[di]; ++di; }
  run_gemm(gm.d[di], blk);
}

// ---- fp32 -> bf16 conversion for x + 18 weight tensors ----
#define NCONV 19
struct ConvMulti { const float* src[NCONV]; u16* dst[NCONV]; int n[NCONV]; int total; };

__global__ __launch_bounds__(256) void k_convert(ConvMulti cm){
  const int stride = gridDim.x * blockDim.x;
  for (int i = blockIdx.x * blockDim.x + threadIdx.x; i < cm.total; i += stride){
    int idx = i, di = 0;
    while (idx >= cm.n[di]){ idx -= cm.n[di]; ++di; }
    cm.dst[di][idx] = f2bf(cm.src[di][idx]);
  }
}

// ---- fused: enc_h(=relu(enc_h1@W2+b2)) + 4 heads + z + KL accum + phi_z ----
__global__ __launch_bounds__(256) void k_enc_fused(
    const u16* __restrict__ enc_h1, const u16* __restrict__ pri_h,
    const u16* __restrict__ enc_w2, const float* __restrict__ enc_b2,
    const u16* __restrict__ enc_mu_w, const float* __restrict__ enc_mu_b,
    const u16* __restrict__ enc_lv_w, const float* __restrict__ enc_lv_b,
    const u16* __restrict__ pri_mu_w, const float* __restrict__ pri_mu_b,
    const u16* __restrict__ pri_lv_w, const float* __restrict__ pri_lv_b,
    const u16* __restrict__ phi_z_w, const float* __restrict__ phi_z_b,
    const float* __restrict__ eps_t, u16* __restrict__ phi_z_out,
    float* __restrict__ kld_acc)
{
  __shared__ u16 enc_h_s[16 * 528];
  __shared__ float head_s[4][16 * 64]; // qmu, qlv, pmu, plv
  __shared__ u16 z_s[16 * 72];
  __shared__ float red[256];
  const int tid = threadIdx.x;
  const int w = tid >> 6, lane = tid & 63, r = lane & 15, g = lane >> 4;
  const int m0 = blockIdx.x * 16;

  { // phase 1: enc_h rows [m0,m0+16), wave w -> cols [w*128, w*128+128)
    f32x4 acc[8];
    #pragma unroll
    for (int i = 0; i < 8; ++i) acc[i] = (f32x4){0.f, 0.f, 0.f, 0.f};
    const int n0 = w * 128;
    mm_acc<8>(enc_h1 + (size_t)(m0 + r) * 512 + g * 8,
              enc_w2 + (size_t)(n0 + r) * 512 + g * 8, 512, 512, acc);
    #pragma unroll
    for (int nt = 0; nt < 8; ++nt)
      #pragma unroll
      for (int i = 0; i < 4; ++i){
        const int row = g * 4 + i, col = n0 + nt * 16 + r;
        float v = fmaxf(acc[nt][i] + enc_b2[col], 0.f);
        enc_h_s[row * 528 + col] = f2bf(v);
      }
  }
  __syncthreads();
  { // phase 2: head GEMM per wave, [16,64] K=512
    f32x4 acc[4];
    #pragma unroll
    for (int i = 0; i < 4; ++i) acc[i] = (f32x4){0.f, 0.f, 0.f, 0.f};
    const u16* ap; int lda; const u16* W; const float* bias; bool clip;
    if      (w == 0){ ap = enc_h_s;                      lda = 528; W = enc_mu_w; bias = enc_mu_b; clip = false; }
    else if (w == 1){ ap = enc_h_s;                      lda = 528; W = enc_lv_w; bias = enc_lv_b; clip = true;  }
    else if (w == 2){ ap = pri_h + (size_t)m0 * 512;     lda = 512; W = pri_mu_w; bias = pri_mu_b; clip = false; }
    else            { ap = pri_h + (size_t)m0 * 512;     lda = 512; W = pri_lv_w; bias = pri_lv_b; clip = true;  }
    mm_acc<4>(ap + (size_t)r * lda + g * 8, W + (size_t)r * 512 + g * 8, 512, 512, acc);
    #pragma unroll
    for (int nt = 0; nt < 4; ++nt)
      #pragma unroll
      for (int i = 0; i < 4; ++i){
        const int row = g * 4 + i, col = nt * 16 + r;
        float v = acc[nt][i] + bias[col];
        if (clip) v = fminf(fmaxf(v, -6.f), 6.f);
        head_s[w][row * 64 + col] = v;
      }
  }
  __syncthreads();
  // phase 3: z + KL
  float klsum = 0.f;
  for (int e = tid; e < 1024; e += 256){
    const int row = e >> 6, col = e & 63;
    const float qm = head_s[0][e], qv = head_s[1][e];
    const float pm = head_s[2][e], pv = head_s[3][e];
    const float zv = qm + eps_t[(size_t)(m0 + row) * 64 + col] * __expf(0.5f * qv);
    z_s[row * 72 + col] = f2bf(zv);
    const float dm = qm - pm;
    klsum += 0.5f * (pv - qv + (__expf(qv) + dm * dm) * __expf(-pv) - 1.0f);
  }
  red[tid] = klsum;
  __syncthreads();
  for (int s = 128; s > 0; s >>= 1){ if (tid < s) red[tid] += red[tid + s]; __syncthreads(); }
  if (tid == 0) atomicAdd(kld_acc, red[0]);
  { // phase 4: phi_z [16,512], wave w -> cols [w*128, w*128+128), K=64
    f32x4 acc[8];
    #pragma unroll
    for (int i = 0; i < 8; ++i) acc[i] = (f32x4){0.f, 0.f, 0.f, 0.f};
    const int n0 = w * 128;
    mm_acc<8>(z_s + (size_t)r * 72 + g * 8,
              phi_z_w + (size_t)(n0 + r) * 64 + g * 8, 64, 64, acc);
    #pragma unroll
    for (int nt = 0; nt < 8; ++nt)
      #pragma unroll
      for (int i = 0; i < 4; ++i){
        const int row = m0 + g * 4 + i, col = n0 + nt * 16 + r;
        float v = fmaxf(acc[nt][i] + phi_z_b[col], 0.f);
        phi_z_out[(size_t)row * 512 + col] = f2bf(v);
      }
  }
}

// ---- L5: dec_h GEMM + GRU layer-0 combine ----
__global__ __launch_bounds__(256) void k_l5(GemmMulti gm,
    const float* __restrict__ gi0, const float* __restrict__ gh0, u16* __restrict__ h0)
{
  if ((int)blockIdx.x < gm.nblk[0]){ run_gemm(gm.d[0], blockIdx.x); return; }
  const int b = blockIdx.x - gm.nblk[0];
  for (int idx = b * 256 + threadIdx.x; idx < 256 * 512; idx += 16 * 256){
    const int row = idx >> 9, col = idx & 511;
    const float* gi = gi0 + (size_t)row * 1536;
    const float* gh = gh0 + (size_t)row * 1536;
    const float rr = sigm(gi[col] + gh[col]);
    const float zg = sigm(gi[col + 512] + gh[col + 512]);
    const float nn = tanh_(gi[col + 1024] + rr * gh[col + 1024]);
    const float hv = (1.f - zg) * nn + zg * bf2f(h0[idx]);
    h0[idx] = f2bf(hv);
  }
}

// ---- L6: gi1 GEMM + dec heads + NLL accumulation ----
__global__ __launch_bounds__(256) void k_l6(GemmMulti gm,
    const u16* __restrict__ dec_h,
    const u16* __restrict__ dmu_w, const float* __restrict__ dmu_b,
    const u16* __restrict__ dlv_w, const float* __restrict__ dlv_b,
    const float* __restrict__ x_t, float* __restrict__ rec_acc)
{
  __shared__ float dmu_s[16 * 128], dlv_s[16 * 128];
  __shared__ float red[256];
  if ((int)blockIdx.x < gm.nblk[0]){ run_gemm(gm.d[0], blockIdx.x); return; }
  const int wg = blockIdx.x - gm.nblk[0];
  const int m0 = wg * 16;
  const int tid = threadIdx.x, w = tid >> 6, lane = tid & 63, r = lane & 15, g = lane >> 4;
  {
    f32x4 acc[4];
    #pragma unroll
    for (int i = 0; i < 4; ++i) acc[i] = (f32x4){0.f, 0.f, 0.f, 0.f};
    const u16* W = (w & 2) ? dlv_w : dmu_w;
    const float* bias = (w & 2) ? dlv_b : dmu_b;
    const int n0 = (w & 1) * 64;
    const bool clip = (w & 2);
    mm_acc<4>(dec_h + (size_t)(m0 + r) * 512 + g * 8,
              W + (size_t)(n0 + r) * 512 + g * 8, 512, 512, acc);
    #pragma unroll
    for (int nt = 0; nt < 4; ++nt)
      #pragma unroll
      for (int i = 0; i < 4; ++i){
        const int row = g * 4 + i, col = n0 + nt * 16 + r;
        float v = acc[nt][i] + bias[col];
        if (clip) v = fminf(fmaxf(v, -6.f), 6.f);
        (clip ? dlv_s : dmu_s)[row * 128 + col] = v;
      }
  }
  __syncthreads();
  float ns = 0.f;
  for (int e = tid; e < 2048; e += 256){
    const int row = e >> 7, col = e & 127;
    const float mu = dmu_s[e], lv = dlv_s[e];
    const float xv = x_t[(size_t)(m0 + row) * 128 + col];
    const float d = xv - mu;
    ns += 0.5f * (lv + d * d * __expf(-lv));
  }
  red[tid] = ns;
  __syncthreads();
  for (int s = 128; s > 0; s >>= 1){ if (tid < s) red[tid] += red[tid + s]; __syncthreads(); }
  if (tid == 0) atomicAdd(rec_acc, red[0]);
}

// ---- L7: GRU layer-1 combine + (last step) finalize ----
__global__ __launch_bounds__(256) void k_l7(const float* __restrict__ gi1,
    const float* __restrict__ gh1, u16* __restrict__ h1,
    int dofinal, const float* __restrict__ accf, float* __restrict__ out)
{
  if ((int)blockIdx.x < 16){
    for (int idx = blockIdx.x * 256 + threadIdx.x; idx < 256 * 512; idx += 16 * 256){
      const int row = idx >> 9, col = idx & 511;
      const float* gi = gi1 + (size_t)row * 1536;
      const float* gh = gh1 + (size_t)row * 1536;
      const float rr = sigm(gi[col] + gh[col]);
      const float zg = sigm(gi[col + 512] + gh[col + 512]);
      const float nn = tanh_(gi[col + 1024] + rr * gh[col + 1024]);
      const float hv = (1.f - zg) * nn + zg * bf2f(h1[idx]);
      h1[idx] = f2bf(hv);
    }
  } else if (dofinal && threadIdx.x == 0){
    const float kl = accf[0] * (1.f / 32768.f); // /B=256 /T=128
    const float rc = accf[1] * (1.f / 32768.f);
    out[0] = rc + kl; out[1] = rc; out[2] = kl;
  }
}

extern "C" void kernel_launch(void* const* d_in, const int* in_sizes, int n_in,
                              void* d_out, int out_size, void* d_ws, size_t ws_size,
                              hipStream_t stream)
{
  (void)in_sizes; (void)n_in; (void)out_size; (void)ws_size;
  const float* x     = (const float*)d_in[0];
  const float* eps   = (const float*)d_in[1];
  const float* w_px1 = (const float*)d_in[2];
  const float* b_px1 = (const float*)d_in[3];
  const float* w_px2 = (const float*)d_in[4];
  const float* b_px2 = (const float*)d_in[5];
  const float* w_pz  = (const float*)d_in[6];
  const float* b_pz  = (const float*)d_in[7];
  const float* w_e1  = (const float*)d_in[8];
  const float* b_e1  = (const float*)d_in[9];
  const float* w_e2  = (const float*)d_in[10];
  const float* b_e2  = (const float*)d_in[11];
  const float* w_emu = (const float*)d_in[12];
  const float* b_emu = (const float*)d_in[13];
  const float* w_elv = (const float*)d_in[14];
  const float* b_elv = (const float*)d_in[15];
  const float* w_pr  = (const float*)d_in[16];
  const float* b_pr  = (const float*)d_in[17];
  const float* w_pmu = (const float*)d_in[18];
  const float* b_pmu = (const float*)d_in[19];
  const float* w_plv = (const float*)d_in[20];
  const float* b_plv = (const float*)d_in[21];
  const float* w_d1  = (const float*)d_in[22];
  const float* b_d1  = (const float*)d_in[23];
  const float* w_d2  = (const float*)d_in[24];
  const float* b_d2  = (const float*)d_in[25];
  const float* w_dmu = (const float*)d_in[26];
  const float* b_dmu = (const float*)d_in[27];
  const float* w_dlv = (const float*)d_in[28];
  const float* b_dlv = (const float*)d_in[29];
  const float* w_ih0 = (const float*)d_in[30];
  const float* w_hh0 = (const float*)d_in[31];
  const float* w_ih1 = (const float*)d_in[32];
  const float* w_hh1 = (const float*)d_in[33];

  char* base = (char*)d_ws;
  size_t off = 0;
  auto alloc = [&](size_t bytes)->char*{
    char* p = base + off;
    off = (off + bytes + 255) & ~(size_t)255;
    return p;
  };
  u16* xbf    = (u16*)alloc((size_t)4194304 * 2);
  u16* cb_px1 = (u16*)alloc((size_t)65536 * 2);
  u16* cb_px2 = (u16*)alloc((size_t)262144 * 2);
  u16* cb_pz  = (u16*)alloc((size_t)32768 * 2);
  u16* cb_e1  = (u16*)alloc((size_t)524288 * 2);
  u16* cb_e2  = (u16*)alloc((size_t)262144 * 2);
  u16* cb_emu = (u16*)alloc((size_t)32768 * 2);
  u16* cb_elv = (u16*)alloc((size_t)32768 * 2);
  u16* cb_pr  = (u16*)alloc((size_t)262144 * 2);
  u16* cb_pmu = (u16*)alloc((size_t)32768 * 2);
  u16* cb_plv = (u16*)alloc((size_t)32768 * 2);
  u16* cb_d1  = (u16*)alloc((size_t)524288 * 2);
  u16* cb_d2  = (u16*)alloc((size_t)262144 * 2);
  u16* cb_dmu = (u16*)alloc((size_t)65536 * 2);
  u16* cb_dlv = (u16*)alloc((size_t)65536 * 2);
  u16* cb_ih0 = (u16*)alloc((size_t)1572864 * 2);
  u16* cb_hh0 = (u16*)alloc((size_t)786432 * 2);
  u16* cb_ih1 = (u16*)alloc((size_t)786432 * 2);
  u16* cb_hh1 = (u16*)alloc((size_t)786432 * 2);
  u16* phiX   = (u16*)alloc((size_t)16777216 * 2);
  // phiX1 region is reused for all per-step buffers after precompute:
  const size_t mark = off;
  u16* phiX1  = (u16*)alloc((size_t)16777216 * 2);
  off = mark;
  u16* a_ench1 = (u16*)alloc((size_t)131072 * 2);
  u16* a_prih  = (u16*)alloc((size_t)131072 * 2);
  u16* a_phiz  = (u16*)alloc((size_t)131072 * 2);
  u16* a_dech1 = (u16*)alloc((size_t)131072 * 2);
  u16* a_dech  = (u16*)alloc((size_t)131072 * 2);
  float* gh0 = (float*)alloc((size_t)393216 * 4);
  float* gh1 = (float*)alloc((size_t)393216 * 4);
  float* gi0 = (float*)alloc((size_t)393216 * 4);
  float* gi1 = (float*)alloc((size_t)393216 * 4);
  u16* h0 = (u16*)alloc((size_t)131072 * 2);
  u16* h1 = (u16*)alloc((size_t)131072 * 2);
  float* accf = (float*)alloc(256);

  // zero h0, h1, accumulators (contiguous allocations)
  hipMemsetAsync(h0, 0, (size_t)131072 * 2 * 2 + 256, stream);

  // convert x + weights to bf16
  ConvMulti cm; int ci = 0, tot = 0;
  auto addc = [&](const float* s, u16* d, int n){ cm.src[ci] = s; cm.dst[ci] = d; cm.n[ci] = n; ++ci; tot += n; };
  addc(x, xbf, 4194304);
  addc(w_px1, cb_px1, 65536);   addc(w_px2, cb_px2, 262144);
  addc(w_pz,  cb_pz,  32768);   addc(w_e1,  cb_e1,  524288);
  addc(w_e2,  cb_e2,  262144);  addc(w_emu, cb_emu, 32768);
  addc(w_elv, cb_elv, 32768);   addc(w_pr,  cb_pr,  262144);
  addc(w_pmu, cb_pmu, 32768);   addc(w_plv, cb_plv, 32768);
  addc(w_d1,  cb_d1,  524288);  addc(w_d2,  cb_d2,  262144);
  addc(w_dmu, cb_dmu, 65536);   addc(w_dlv, cb_dlv, 65536);
  addc(w_ih0, cb_ih0, 1572864); addc(w_hh0, cb_hh0, 786432);
  addc(w_ih1, cb_ih1, 786432);  addc(w_hh1, cb_hh1, 786432);
  cm.total = tot;
  k_convert<<<2048, 256, 0, stream>>>(cm);

  auto D = [](const u16* A, int lda, const u16* A2, int lda2, const u16* W, int ldw,
              const float* bias, void* out, int ldo, int N, int K, int K2, int flags)->GemmDesc{
    GemmDesc d; d.A = A; d.A2 = A2; d.W = W; d.bias = bias; d.out = out;
    d.lda = lda; d.lda2 = lda2; d.ldw = ldw; d.ldo = ldo;
    d.N = N; d.K = K; d.K2 = K2; d.flags = flags; return d;
  };

  { // precompute phi_x over all T*B rows
    GemmMulti g; g.ndesc = 1;
    g.d[0] = D(xbf, 128, nullptr, 0, cb_px1, 128, b_px1, phiX1, 512, 512, 128, 0, 3);
    g.nblk[0] = 512 * 8;
    k_gemm_multi<<<512 * 8, 256, 0, stream>>>(g);
    g.d[0] = D(phiX1, 512, nullptr, 0, cb_px2, 512, b_px2, phiX, 512, 512, 512, 0, 3);
    k_gemm_multi<<<512 * 8, 256, 0, stream>>>(g);
  }

  for (int t = 0; t < 128; ++t){
    const u16* phiXt  = phiX + (size_t)t * 131072;
    const float* epst = eps  + (size_t)t * 16384;
    const float* xt   = x    + (size_t)t * 32768;

    GemmMulti g1; g1.ndesc = 4;
    g1.d[0] = D(phiXt, 512, h1, 512, cb_e1, 1024, b_e1, a_ench1, 512, 512, 512, 512, 3); g1.nblk[0] = 32;
    g1.d[1] = D(h1, 512, nullptr, 0, cb_pr, 512, b_pr, a_prih, 512, 512, 512, 0, 3);     g1.nblk[1] = 32;
    g1.d[2] = D(h1, 512, nullptr, 0, cb_hh1, 512, nullptr, gh1, 1536, 1536, 512, 0, 0);  g1.nblk[2] = 96;
    g1.d[3] = D(h0, 512, nullptr, 0, cb_hh0, 512, nullptr, gh0, 1536, 1536, 512, 0, 0);  g1.nblk[3] = 96;
    k_gemm_multi<<<256, 256, 0, stream>>>(g1);

    k_enc_fused<<<16, 256, 0, stream>>>(a_ench1, a_prih, cb_e2, b_e2,
        cb_emu, b_emu, cb_elv, b_elv, cb_pmu, b_pmu, cb_plv, b_plv,
        cb_pz, b_pz, epst, a_phiz, accf + 0);

    GemmMulti g4; g4.ndesc = 2;
    g4.d[0] = D(a_phiz, 512, h1, 512, cb_d1, 1024, b_d1, a_dech1, 512, 512, 512, 512, 3);  g4.nblk[0] = 32;
    g4.d[1] = D(phiXt, 512, a_phiz, 512, cb_ih0, 1024, nullptr, gi0, 1536, 1536, 512, 512, 0); g4.nblk[1] = 96;
    k_gemm_multi<<<128, 256, 0, stream>>>(g4);

    GemmMulti g5; g5.ndesc = 1;
    g5.d[0] = D(a_dech1, 512, nullptr, 0, cb_d2, 512, b_d2, a_dech, 512, 512, 512, 0, 3); g5.nblk[0] = 32;
    k_l5<<<48, 256, 0, stream>>>(g5, gi0, gh0, h0);

    GemmMulti g6; g6.ndesc = 1;
    g6.d[0] = D(h0, 512, nullptr, 0, cb_ih1, 512, nullptr, gi1, 1536, 1536, 512, 0, 0); g6.nblk[0] = 96;
    k_l6<<<112, 256, 0, stream>>>(g6, a_dech, cb_dmu, b_dmu, cb_dlv, b_dlv, xt, accf + 1);

    k_l7<<<17, 256, 0, stream>>>(gi1, gh1, h1, (t == 127) ? 1 : 0, accf, (float*)d_out);
  }
}